// Round 13
// baseline (84.855 us; speedup 1.0000x reference)
//
#include <hip/hip_runtime.h>
#include <hip/hip_bf16.h>
#include <stdint.h>

typedef __attribute__((ext_vector_type(8))) short bf16x8;
typedef __attribute__((ext_vector_type(4))) float f32x4;
typedef __attribute__((ext_vector_type(16))) float f32x16;
typedef __attribute__((ext_vector_type(2))) unsigned int uint32x2;
typedef __attribute__((address_space(3))) void lds_t;
typedef __attribute__((address_space(1))) void glb_t;

#define B_ 4
#define S_ 2048
#define E_ 1024
#define M_ (B_*S_)
#define QTS 152   // qt row stride: 304 B = 12 banks -> 2-way (free) on b128 reads
#define PPB 8     // positions per block (one 128B output line per row)
#define QSZ 3472  // per-position LDS: qp 1032 el (pad to 1040) + qt 16*152
#define WBS 140   // writeout row stride in BYTES: 35 banks, 3*l31 mod 32 spread

static __device__ __forceinline__ ushort f2bf(float f) {
  uint32_t u = __float_as_uint(f);
  u += 0x7fffu + ((u >> 16) & 1u);
  return (ushort)(u >> 16);
}

static __device__ __forceinline__ uint32_t pk_bf16(float lo, float hi) {
  uint32_t r;
  asm("v_cvt_pk_bf16_f32 %0, %1, %2" : "=v"(r) : "v"(lo), "v"(hi));
  return r;
}
static __device__ __forceinline__ float fexp2(float x) {
  float r;
  asm("v_exp_f32 %0, %1" : "=v"(r) : "v"(x));
  return r;
}

// X = [a_lo | b_lo], Y = [a_hi | b_hi]  (lane halves), convention-proof.
static __device__ __forceinline__ void half_zip(uint32_t a, uint32_t b, bool convA,
                                                uint32_t& X, uint32_t& Y) {
  if (convA) {
    uint32x2 r = __builtin_amdgcn_permlane32_swap(b, a, false, false);
    Y = r[0]; X = r[1];
  } else {
    uint32x2 r = __builtin_amdgcn_permlane32_swap(a, b, false, false);
    X = r[0]; Y = r[1];
  }
}

// ---------------- Stage 1: quantum head-attention via MFMA ----------------
// PPB=8 positions/block (same (b, s>>7) group -> block owns 128 output rows
// x 128B contiguous). Gen all 8 up-front (loads overlap), ONE barrier, then
// 8x R12-green consume chains; epilogue STASHES uint2 per position in regs
// (static-indexed). Writeout: barrier -> stage via LDS (WBS=140B rows,
// conflict-free) -> linear global stores (thread t: 64B of row t>>1) ->
// full 128B lines, 8x fewer write transactions than per-position scatter.
// Green invariants: 256 thr, bare __launch_bounds__(256), wave = quadrant.
__global__ __launch_bounds__(256) void qattn(const float* __restrict__ x,
                                             const float* __restrict__ theta,
                                             ushort* __restrict__ outr) {
  const int wave = threadIdx.x >> 6;
  const int lane = threadIdx.x & 63;
  const int l31 = lane & 31, hw = lane >> 5;

  // XCD-aware swizzle (1024 = 8 x 128, bijective)
  const int bid = blockIdx.x;
  const int oct = (bid & 7) * 128 + (bid >> 3);
  const int base = oct * PPB;                    // 8-aligned; never crosses s/128 group
  const int b = base >> 11;
  const int s0 = base & 2047;
  const int sr = s0 >> 7, scol0 = s0 & 127;

  __shared__ __align__(16) ushort qALL[PPB * QSZ];   // 55.5 KB; aliased by writeout buf

  // permlane32_swap convention probe (wave-uniform)
  uint32x2 pr = __builtin_amdgcn_permlane32_swap((uint32_t)lane, (uint32_t)(lane + 1000),
                                                 false, false);
  const bool convA = (__builtin_amdgcn_readfirstlane((int)pr[0]) >= 1000);

  // ---- gen all 8 positions (loads first, all overlapping) ----
  const int gh  = 32 * wave + (lane >> 1);
  const int gdh = (lane & 1) * 4;
  float4 xv[PPB];
  #pragma unroll
  for (int pp = 0; pp < PPB; ++pp)
    xv[pp] = *(const float4*)(x + (size_t)(base + pp) * E_ + gh * 8 + gdh);

  const float QS = 0.71419165f;   // sqrt((1/sqrt(8)) * log2(e))
  #pragma unroll
  for (int pp = 0; pp < PPB; ++pp) {
    ushort* qpg = qALL + pp * QSZ;
    ushort* qtg = qpg + 1040;
    float q[4];
    q[0] = __cosf(xv[pp].x + theta[gdh + 0]);
    q[1] = __cosf(xv[pp].y + theta[gdh + 1]);
    q[2] = __cosf(xv[pp].z + theta[gdh + 2]);
    q[3] = __cosf(xv[pp].w + theta[gdh + 3]);
    uint2 pw;
    pw.x = pk_bf16(q[0] * QS, q[1] * QS);
    pw.y = pk_bf16(q[2] * QS, q[3] * QS);
    *(uint2*)(qpg + gh * 8 + gdh) = pw;                    // scaled, for QK^T
    #pragma unroll
    for (int j = 0; j < 4; ++j)                            // raw, for PV A-operand
      qtg[(gdh + j) * QTS + gh] = f2bf(q[j]);
    qtg[(8 + gdh) * QTS + gh] = (ushort)0x3F80u;           // ones row 8 / 12
    if (lane == 0) *(uint4*)(qpg + 128 * 8) = make_uint4(0, 0, 0, 0);  // K-pad row
  }
  __syncthreads();
  __builtin_amdgcn_sched_barrier(0);

  const int hi = wave;
  uint2 o_st[PPB];   // stashed per-position outputs (static-indexed)

  #pragma unroll
  for (int pp = 0; pp < PPB; ++pp) {
    const ushort* qp = qALL + pp * QSZ;
    const ushort* qt = qp + 1040;

    bf16x8 aqv[4];
    #pragma unroll
    for (int gj = 0; gj < 4; ++gj) {
      const int arow = (lane < 32) ? (gj * 32 + l31) : 128;
      aqv[gj] = *(const bf16x8*)(qp + arow * 8);
    }
    const int brow = (lane < 32) ? (hi * 32 + l31) : 128;
    const bf16x8 bq = *(const bf16x8*)(qp + brow * 8);
    const ushort* qtb = qt + (l31 & 15) * QTS + hw * 8;

    f32x16 oaccA = {}, oaccB = {};

    #pragma unroll
    for (int gj = 0; gj < 4; ++gj) {
      f32x16 sc = {};
      sc = __builtin_amdgcn_mfma_f32_32x32x16_bf16(aqv[gj], bq, sc, 0, 0, 0);
      const bf16x8 fA = *(const bf16x8*)(qtb + (gj * 2 + 0) * 16);
      const bf16x8 fB = *(const bf16x8*)(qtb + (gj * 2 + 1) * 16);
      float pv[16];
      #pragma unroll
      for (int k = 0; k < 16; ++k) pv[k] = fexp2(sc[k]);
      #pragma unroll
      for (int sl = 0; sl < 2; ++sl) {
        const int pb = sl * 8;
        const uint32_t u = pk_bf16(pv[pb+0], pv[pb+1]);
        const uint32_t v = pk_bf16(pv[pb+2], pv[pb+3]);
        const uint32_t w = pk_bf16(pv[pb+4], pv[pb+5]);
        const uint32_t z = pk_bf16(pv[pb+6], pv[pb+7]);
        uint32_t f0, f1, f2, f3;
        half_zip(u, w, convA, f0, f2);
        half_zip(v, z, convA, f1, f3);
        uint32_t fr[4] = {f0, f1, f2, f3};
        if (gj < 2)
          oaccA = __builtin_amdgcn_mfma_f32_32x32x16_bf16((sl == 0) ? fA : fB,
                                                          *(const bf16x8*)fr, oaccA, 0, 0, 0);
        else
          oaccB = __builtin_amdgcn_mfma_f32_32x32x16_bf16((sl == 0) ? fA : fB,
                                                          *(const bf16x8*)fr, oaccB, 0, 0, 0);
      }
    }
    const f32x16 oacc = oaccA + oaccB;

    const float inv = __builtin_amdgcn_rcpf(oacc[4]);
    o_st[pp] = make_uint2(pk_bf16(oacc[0] * inv, oacc[1] * inv),
                          pk_bf16(oacc[2] * inv, oacc[3] * inv));
  }
  __syncthreads();                    // all consumes done -> q LDS reusable

  // ---- writeout staging: wbuf[h][colw] (row stride WBS bytes) ----
  char* wbuf = (char*)qALL;
  {
    const int h_loc = hi * 32 + l31;
    #pragma unroll
    for (int pp = 0; pp < PPB; ++pp)
      *(uint2*)(wbuf + h_loc * WBS + pp * 16 + hw * 8) = o_st[pp];
  }
  __syncthreads();

  // ---- linear global write: thread t -> 64B of row t>>1 (full 128B lines) ----
  {
    const int t = (int)threadIdx.x;
    const int h_loc = t >> 1, half = t & 1;
    const size_t grow = (size_t)(b * 2048 + h_loc * 16 + sr);
    ushort* gp = outr + grow * E_ + scol0 * 8 + half * 32;
    const char* lp = wbuf + h_loc * WBS + half * 64;
    #pragma unroll
    for (int c = 0; c < 4; ++c)
      *(uint4*)(gp + c * 8) = *(const uint4*)(lp + c * 16);
  }
}

// ---------------- W (f32) -> bf16 ----------------
__global__ __launch_bounds__(256) void wconv(const float* __restrict__ W,
                                             ushort* __restrict__ Wb) {
  const int i = blockIdx.x * 256 + threadIdx.x;
  const float4 v = ((const float4*)W)[i];
  ushort4 o;
  o.x = f2bf(v.x); o.y = f2bf(v.y); o.z = f2bf(v.z); o.w = f2bf(v.w);
  ((ushort4*)Wb)[i] = o;
}

// ---------------- Stage 2: C[m,n] = sum_k A[m,k]*W[n,k] + bias[n] ----------------
// Double-buffered 2-phase (R12-green).
__global__ __launch_bounds__(256) void gemm_bt(const ushort* __restrict__ A,
                                               const ushort* __restrict__ Bw,
                                               const float* __restrict__ bias,
                                               float* __restrict__ C) {
  __shared__ __align__(16) ushort As[2][128 * 32];
  __shared__ __align__(16) ushort Bs[2][128 * 32];

  const int t = threadIdx.x;
  const int lane = t & 63;
  const int wavei = t >> 6;
  const int wr = wavei >> 1, wc = wavei & 1;
  const int lhi = lane >> 4, llo = lane & 15;
  const size_t ar0 = (size_t)blockIdx.x * 128;
  const size_t br0 = (size_t)blockIdx.y * 128;

  const int c0 = t, c1 = t + 256;
  const int r0 = c0 >> 2, kp0 = (c0 & 3) * 8;
  const int r1 = c1 >> 2, kp1 = (c1 & 3) * 8;

  auto stage = [&](int buf, int k0) {
    __builtin_amdgcn_global_load_lds((const glb_t*)(A  + (ar0 + r0) * E_ + k0 + kp0),
                                     (lds_t*)(As[buf] + c0 * 8), 16, 0, 0);
    __builtin_amdgcn_global_load_lds((const glb_t*)(A  + (ar0 + r1) * E_ + k0 + kp1),
                                     (lds_t*)(As[buf] + c1 * 8), 16, 0, 0);
    __builtin_amdgcn_global_load_lds((const glb_t*)(Bw + (br0 + r0) * E_ + k0 + kp0),
                                     (lds_t*)(Bs[buf] + c0 * 8), 16, 0, 0);
    __builtin_amdgcn_global_load_lds((const glb_t*)(Bw + (br0 + r1) * E_ + k0 + kp1),
                                     (lds_t*)(Bs[buf] + c1 * 8), 16, 0, 0);
  };

  f32x4 acc[4][4] = {};

  stage(0, 0);
  __syncthreads();

  for (int k0 = 0; k0 < E_; k0 += 32) {
    const int cur = (k0 >> 5) & 1;
    if (k0 + 32 < E_) stage(cur ^ 1, k0 + 32);

    bf16x8 af[4], bfr[4];
    #pragma unroll
    for (int i = 0; i < 4; ++i)
      af[i] = *(const bf16x8*)(As[cur] + (wr * 64 + i * 16 + llo) * 32 + lhi * 8);
    #pragma unroll
    for (int j = 0; j < 4; ++j)
      bfr[j] = *(const bf16x8*)(Bs[cur] + (wc * 64 + j * 16 + llo) * 32 + lhi * 8);

    #pragma unroll
    for (int i = 0; i < 4; ++i)
      #pragma unroll
      for (int j = 0; j < 4; ++j)
        acc[i][j] = __builtin_amdgcn_mfma_f32_16x16x32_bf16(af[i], bfr[j], acc[i][j], 0, 0, 0);

    __syncthreads();
  }

  #pragma unroll
  for (int j = 0; j < 4; ++j) {
    const int n = (int)br0 + wc * 64 + j * 16 + llo;
    const float bj = bias[n];
    #pragma unroll
    for (int i = 0; i < 4; ++i) {
      const int mb = (int)ar0 + wr * 64 + i * 16 + lhi * 4;
      #pragma unroll
      for (int r = 0; r < 4; ++r) {
        C[(size_t)(mb + r) * E_ + n] = acc[i][j][r] + bj;
      }
    }
  }
}

extern "C" void kernel_launch(void* const* d_in, const int* in_sizes, int n_in,
                              void* d_out, int out_size, void* d_ws, size_t ws_size,
                              hipStream_t stream) {
  const float* x     = (const float*)d_in[0];
  const float* theta = (const float*)d_in[1];
  const float* W     = (const float*)d_in[2];
  const float* bias  = (const float*)d_in[3];
  float* out = (float*)d_out;

  ushort* outr = (ushort*)d_ws;
  ushort* Wb   = (ushort*)((char*)d_ws + (size_t)M_ * E_ * 2);

  qattn<<<M_ / PPB, 256, 0, stream>>>(x, theta, outr);
  wconv<<<(E_ * E_) / (256 * 4), 256, 0, stream>>>(W, Wb);
  dim3 g(M_ / 128, E_ / 128);
  gemm_bt<<<g, 256, 0, stream>>>(outr, Wb, bias, out);
}

// Round 14
// 73.780 us; speedup vs baseline: 1.1501x; 1.1501x over previous
//
#include <hip/hip_runtime.h>
#include <hip/hip_bf16.h>
#include <stdint.h>

typedef __attribute__((ext_vector_type(8))) short bf16x8;
typedef __attribute__((ext_vector_type(4))) float f32x4;
typedef __attribute__((ext_vector_type(16))) float f32x16;
typedef __attribute__((ext_vector_type(2))) unsigned int uint32x2;
typedef __attribute__((address_space(3))) void lds_t;
typedef __attribute__((address_space(1))) void glb_t;

#define B_ 4
#define S_ 2048
#define E_ 1024
#define M_ (B_*S_)
#define QTS 152   // qt row stride: 304 B = 12 banks -> 2-way (free) on b128 reads

static __device__ __forceinline__ ushort f2bf(float f) {
  uint32_t u = __float_as_uint(f);
  u += 0x7fffu + ((u >> 16) & 1u);
  return (ushort)(u >> 16);
}

static __device__ __forceinline__ uint32_t pk_bf16(float lo, float hi) {
  uint32_t r;
  asm("v_cvt_pk_bf16_f32 %0, %1, %2" : "=v"(r) : "v"(lo), "v"(hi));
  return r;
}
static __device__ __forceinline__ float fexp2(float x) {
  float r;
  asm("v_exp_f32 %0, %1" : "=v"(r) : "v"(x));
  return r;
}

// X = [a_lo | b_lo], Y = [a_hi | b_hi]  (lane halves), convention-proof.
static __device__ __forceinline__ void half_zip(uint32_t a, uint32_t b, bool convA,
                                                uint32_t& X, uint32_t& Y) {
  if (convA) {
    uint32x2 r = __builtin_amdgcn_permlane32_swap(b, a, false, false);
    Y = r[0]; X = r[1];
  } else {
    uint32x2 r = __builtin_amdgcn_permlane32_swap(a, b, false, false);
    X = r[0]; Y = r[1];
  }
}

// ---------------- Stage 1: quantum head-attention via MFMA ----------------
// SINGLE-WAVE blocks: 64 thr = 1 wave = 1 position, wave-private LDS, ZERO
// barriers (intra-wave LDS deps tracked by compiler lgkmcnt — R3-green
// precedent). Purpose: maximize independent chains per CU (up to 16+ resident
// blocks vs 2.5 with 4-wave blocks) to hide the per-gj MFMA->exp->pack->zip
// serial chain. Gen: R3-green pattern (lane covers heads 2l, 2l+1; 16 cos).
// Consume: R12-green dataflow iterated over all 4 head-quadrants hi.
__global__ __launch_bounds__(64) void qattn(const float* __restrict__ x,
                                            const float* __restrict__ theta,
                                            ushort* __restrict__ outr) {
  const int lane = threadIdx.x & 63;
  const int l31 = lane & 31, hw = lane >> 5;

  // XCD-aware swizzle (8192 = 8 x 1024, bijective)
  const int bid = blockIdx.x;
  const int bs = (bid & 7) * 1024 + (bid >> 3);
  const int b = bs >> 11, s = bs & 2047;

  __shared__ __align__(16) ushort qp[129 * 8];    // scaled q, row 128 = zeros (K-pad)
  __shared__ __align__(16) ushort qt[16 * QTS];   // raw q^T, ones rows 8 & 12

  // permlane32_swap convention probe (wave-uniform)
  uint32x2 pr = __builtin_amdgcn_permlane32_swap((uint32_t)lane, (uint32_t)(lane + 1000),
                                                 false, false);
  const bool convA = (__builtin_amdgcn_readfirstlane((int)pr[0]) >= 1000);

  // ---- gen: lane covers heads 2*lane (xr[0..7]) and 2*lane+1 (xr[8..15]) ----
  {
    float th[8];
    #pragma unroll
    for (int d = 0; d < 8; ++d) th[d] = theta[d];

    const float* xp = x + (size_t)bs * E_ + lane * 16;
    float xr[16];
    #pragma unroll
    for (int i = 0; i < 4; ++i) {
      const float4 v = ((const float4*)xp)[i];
      xr[4*i+0] = v.x; xr[4*i+1] = v.y; xr[4*i+2] = v.z; xr[4*i+3] = v.w;
    }
    float q0[8], q1[8];
    #pragma unroll
    for (int d = 0; d < 8; ++d) {
      q0[d] = __cosf(xr[d] + th[d]);
      q1[d] = __cosf(xr[8 + d] + th[d]);
    }

    // QS^2 = (1/sqrt(8)) * log2(e): folds softmax scale + exp->exp2 into QK operands
    const float QS = 0.71419165f;
    uint32_t qw[8];
    #pragma unroll
    for (int i = 0; i < 4; ++i) {
      qw[i]     = pk_bf16(q0[2*i] * QS, q0[2*i+1] * QS);
      qw[4 + i] = pk_bf16(q1[2*i] * QS, q1[2*i+1] * QS);
    }
    *(uint4*)(qp + (2*lane)     * 8) = *(uint4*)&qw[0];
    *(uint4*)(qp + (2*lane + 1) * 8) = *(uint4*)&qw[4];
    if (lane == 0) *(uint4*)(qp + 128 * 8) = make_uint4(0, 0, 0, 0);   // K-pad row

    // qt raw: qt[d][g] pairs (g = 2*lane, 2*lane+1); ones rows 8 & 12 only
    #pragma unroll
    for (int d = 0; d < 8; ++d)
      *(uint32_t*)(qt + d * QTS + 2 * lane) = pk_bf16(q0[d], q1[d]);
    *(uint32_t*)(qt + 8  * QTS + 2 * lane) = 0x3F803F80u;
    *(uint32_t*)(qt + 12 * QTS + 2 * lane) = 0x3F803F80u;
  }
  // no barrier: wave-private LDS, compiler tracks lgkm deps

  // prefetch A-row frags (shared across all hi) + PV A-frag base
  bf16x8 aqv[4];
  #pragma unroll
  for (int gj = 0; gj < 4; ++gj) {
    const int arow = (lane < 32) ? (gj * 32 + l31) : 128;
    aqv[gj] = *(const bf16x8*)(qp + arow * 8);
  }
  const ushort* qtb = qt + (l31 & 15) * QTS + hw * 8;
  bf16x8 pvf[8];
  #pragma unroll
  for (int ks = 0; ks < 8; ++ks)
    pvf[ks] = *(const bf16x8*)(qtb + ks * 16);

  const int scol = s & 127, srow = s >> 7;

  #pragma unroll
  for (int hi = 0; hi < 4; ++hi) {
    const int brow = (lane < 32) ? (hi * 32 + l31) : 128;
    const bf16x8 bq = *(const bf16x8*)(qp + brow * 8);

    f32x16 oaccA = {}, oaccB = {};   // two 4-deep PV chains

    #pragma unroll
    for (int gj = 0; gj < 4; ++gj) {
      f32x16 sc = {};
      sc = __builtin_amdgcn_mfma_f32_32x32x16_bf16(aqv[gj], bq, sc, 0, 0, 0);
      float pv[16];
      #pragma unroll
      for (int k = 0; k < 16; ++k) pv[k] = fexp2(sc[k]);
      #pragma unroll
      for (int sl = 0; sl < 2; ++sl) {
        const int pb = sl * 8;
        const uint32_t u = pk_bf16(pv[pb+0], pv[pb+1]);
        const uint32_t v = pk_bf16(pv[pb+2], pv[pb+3]);
        const uint32_t w = pk_bf16(pv[pb+4], pv[pb+5]);
        const uint32_t z = pk_bf16(pv[pb+6], pv[pb+7]);
        uint32_t f0, f1, f2, f3;
        half_zip(u, w, convA, f0, f2);
        half_zip(v, z, convA, f1, f3);
        uint32_t fr[4] = {f0, f1, f2, f3};
        if (gj < 2)
          oaccA = __builtin_amdgcn_mfma_f32_32x32x16_bf16(pvf[gj*2 + sl],
                                                          *(const bf16x8*)fr, oaccA, 0, 0, 0);
        else
          oaccB = __builtin_amdgcn_mfma_f32_32x32x16_bf16(pvf[gj*2 + sl],
                                                          *(const bf16x8*)fr, oaccB, 0, 0, 0);
      }
    }
    const f32x16 oacc = oaccA + oaccB;

    // epilogue: regs0-3 = d 0-3 (hw=0) / d 4-7 (hw=1); reg4 = rowsum (both halves)
    const float inv = __builtin_amdgcn_rcpf(oacc[4]);
    const uint32_t o01 = pk_bf16(oacc[0] * inv, oacc[1] * inv);
    const uint32_t o23 = pk_bf16(oacc[2] * inv, oacc[3] * inv);
    const int h = hi * 32 + l31;
    const size_t row = (size_t)(b * 2048 + h * 16 + srow);
    *(uint2*)(outr + row * E_ + scol * 8 + hw * 4) = make_uint2(o01, o23);
  }
}

// ---------------- W (f32) -> bf16 ----------------
__global__ __launch_bounds__(256) void wconv(const float* __restrict__ W,
                                             ushort* __restrict__ Wb) {
  const int i = blockIdx.x * 256 + threadIdx.x;
  const float4 v = ((const float4*)W)[i];
  ushort4 o;
  o.x = f2bf(v.x); o.y = f2bf(v.y); o.z = f2bf(v.z); o.w = f2bf(v.w);
  ((ushort4*)Wb)[i] = o;
}

// ---------------- Stage 2: C[m,n] = sum_k A[m,k]*W[n,k] + bias[n] ----------------
// Double-buffered 2-phase (R12-green).
__global__ __launch_bounds__(256) void gemm_bt(const ushort* __restrict__ A,
                                               const ushort* __restrict__ Bw,
                                               const float* __restrict__ bias,
                                               float* __restrict__ C) {
  __shared__ __align__(16) ushort As[2][128 * 32];
  __shared__ __align__(16) ushort Bs[2][128 * 32];

  const int t = threadIdx.x;
  const int lane = t & 63;
  const int wavei = t >> 6;
  const int wr = wavei >> 1, wc = wavei & 1;
  const int lhi = lane >> 4, llo = lane & 15;
  const size_t ar0 = (size_t)blockIdx.x * 128;
  const size_t br0 = (size_t)blockIdx.y * 128;

  const int c0 = t, c1 = t + 256;
  const int r0 = c0 >> 2, kp0 = (c0 & 3) * 8;
  const int r1 = c1 >> 2, kp1 = (c1 & 3) * 8;

  auto stage = [&](int buf, int k0) {
    __builtin_amdgcn_global_load_lds((const glb_t*)(A  + (ar0 + r0) * E_ + k0 + kp0),
                                     (lds_t*)(As[buf] + c0 * 8), 16, 0, 0);
    __builtin_amdgcn_global_load_lds((const glb_t*)(A  + (ar0 + r1) * E_ + k0 + kp1),
                                     (lds_t*)(As[buf] + c1 * 8), 16, 0, 0);
    __builtin_amdgcn_global_load_lds((const glb_t*)(Bw + (br0 + r0) * E_ + k0 + kp0),
                                     (lds_t*)(Bs[buf] + c0 * 8), 16, 0, 0);
    __builtin_amdgcn_global_load_lds((const glb_t*)(Bw + (br0 + r1) * E_ + k0 + kp1),
                                     (lds_t*)(Bs[buf] + c1 * 8), 16, 0, 0);
  };

  f32x4 acc[4][4] = {};

  stage(0, 0);
  __syncthreads();

  for (int k0 = 0; k0 < E_; k0 += 32) {
    const int cur = (k0 >> 5) & 1;
    if (k0 + 32 < E_) stage(cur ^ 1, k0 + 32);

    bf16x8 af[4], bfr[4];
    #pragma unroll
    for (int i = 0; i < 4; ++i)
      af[i] = *(const bf16x8*)(As[cur] + (wr * 64 + i * 16 + llo) * 32 + lhi * 8);
    #pragma unroll
    for (int j = 0; j < 4; ++j)
      bfr[j] = *(const bf16x8*)(Bs[cur] + (wc * 64 + j * 16 + llo) * 32 + lhi * 8);

    #pragma unroll
    for (int i = 0; i < 4; ++i)
      #pragma unroll
      for (int j = 0; j < 4; ++j)
        acc[i][j] = __builtin_amdgcn_mfma_f32_16x16x32_bf16(af[i], bfr[j], acc[i][j], 0, 0, 0);

    __syncthreads();
  }

  #pragma unroll
  for (int j = 0; j < 4; ++j) {
    const int n = (int)br0 + wc * 64 + j * 16 + llo;
    const float bj = bias[n];
    #pragma unroll
    for (int i = 0; i < 4; ++i) {
      const int mb = (int)ar0 + wr * 64 + i * 16 + lhi * 4;
      #pragma unroll
      for (int r = 0; r < 4; ++r) {
        C[(size_t)(mb + r) * E_ + n] = acc[i][j][r] + bj;
      }
    }
  }
}

extern "C" void kernel_launch(void* const* d_in, const int* in_sizes, int n_in,
                              void* d_out, int out_size, void* d_ws, size_t ws_size,
                              hipStream_t stream) {
  const float* x     = (const float*)d_in[0];
  const float* theta = (const float*)d_in[1];
  const float* W     = (const float*)d_in[2];
  const float* bias  = (const float*)d_in[3];
  float* out = (float*)d_out;

  ushort* outr = (ushort*)d_ws;
  ushort* Wb   = (ushort*)((char*)d_ws + (size_t)M_ * E_ * 2);

  qattn<<<M_, 64, 0, stream>>>(x, theta, outr);
  wconv<<<(E_ * E_) / (256 * 4), 256, 0, stream>>>(W, Wb);
  dim3 g(M_ / 128, E_ / 128);
  gemm_bt<<<g, 256, 0, stream>>>(outr, Wb, bias, out);
}